// Round 2
// baseline (148.545 us; speedup 1.0000x reference)
//
#include <hip/hip_runtime.h>
#include <math.h>

#define B_SZ 16384
#define D_DIM 128
#define A_SZ 8192
#define K_SZ 64
#define L2_REG_F 0.25f
#define CONV_BLK 512   // convert kernel blocks (x4 waves -> 8 rows/wave)
#define NBLK 2048      // main kernel blocks: 1 wave per anchor
#define NPART (CONV_BLK + NBLK)

typedef float vfloat2 __attribute__((ext_vector_type(2)));

__device__ __forceinline__ float wave_reduce_sum(float v) {
    #pragma unroll
    for (int off = 32; off > 0; off >>= 1)
        v += __shfl_xor(v, off, 64);
    return v;
}

__device__ __forceinline__ float wave_reduce_max(float v) {
    #pragma unroll
    for (int off = 32; off > 0; off >>= 1)
        v = fmaxf(v, __shfl_xor(v, off, 64));
    return v;
}

// Pre-pass: fp32 table -> fp8 e4m3 table (2 MB, L2-resident) fused with the
// exact-fp32 L2-norm sum (the only full streaming read of the fp32 table).
// Also zeroes the last-block-done counter for the main kernel.
__global__ __launch_bounds__(256) void convert_kernel(const float* __restrict__ embed,
                                                      unsigned short* __restrict__ tab,
                                                      float* __restrict__ partial,
                                                      unsigned* __restrict__ counter) {
    if (blockIdx.x == 0 && threadIdx.x == 0) *counter = 0u;
    __shared__ float red[4];
    const int wave = threadIdx.x >> 6;
    const int lane = threadIdx.x & 63;
    const int gw   = blockIdx.x * 4 + wave;           // 0..2047
    float acc = 0.f;
    #pragma unroll
    for (int r = 0; r < B_SZ / (CONV_BLK * 4); ++r) { // 8 contiguous rows/wave
        const int row = gw * (B_SZ / (CONV_BLK * 4)) + r;
        const float2* rr = (const float2*)(embed + (size_t)row * D_DIM);
        float2 v = rr[lane];                          // elems 2*lane, 2*lane+1
        acc += sqrtf(wave_reduce_sum(v.x * v.x + v.y * v.y));  // exact fp32 norm
        // HW RNE fp32->fp8 e4m3 (OCP on gfx950), 2 elems packed in low ushort
        unsigned pk = (unsigned)__builtin_amdgcn_cvt_pk_fp8_f32(v.x, v.y, 0, false);
        tab[(size_t)row * 64 + lane] = (unsigned short)pk;
    }
    if (lane == 0) red[wave] = acc * (L2_REG_F / (float)B_SZ); // pre-scaled
    __syncthreads();
    if (threadIdx.x == 0)
        partial[blockIdx.x] = red[0] + red[1] + red[2] + red[3];
}

// Main: one wave per anchor. 8 lanes (a "group") cooperate per negative row
// (row = 128 B; lane (g,c) reads 16B chunk c). Pass p covers rows g*8+p, so
// each lane's 8 row indices are CONTIGUOUS -> loaded directly as 2x int4
// (no ds_bpermute). Per-pass partials are kept in registers and combined by
// a 3-round butterfly transpose-reduce (7 shfl instead of 24). a/p chunks
// are loaded directly from global (wave-uniform rows -> L1 broadcast); no
// LDS round-trip. Last block performs the final reduction (no finalize
// launch).
__global__ __launch_bounds__(256) void npair_kernel(const float* __restrict__ embed,
                                                    const unsigned short* __restrict__ tab,
                                                    const int* __restrict__ anc_ind,
                                                    const int* __restrict__ pos_ind,
                                                    const int* __restrict__ neg_ind,
                                                    float* partial,
                                                    unsigned* counter,
                                                    float* out) {
    __shared__ float red[4];
    __shared__ unsigned last_flag;
    const int wave = threadIdx.x >> 6;
    const int lane = threadIdx.x & 63;
    const int i    = blockIdx.x * 4 + wave;           // anchor id 0..8191
    const int g    = lane >> 3;   // group 0..7 (8 consecutive lanes per row)
    const int c    = lane & 7;    // 16B chunk 0..7 within the 128B row

    // --- independent loads first: indices (lane-own, contiguous) + a/p chunks ---
    const int4* nb = (const int4*)(neg_ind + (size_t)i * K_SZ + g * 8);
    int4 nlo = nb[0], nhi = nb[1];

    const int ai = anc_ind[i];                        // wave-uniform
    const int pi = pos_ind[i];
    const float4* arow = (const float4*)(embed + (size_t)ai * D_DIM) + c * 4;
    const float4* prow = (const float4*)(embed + (size_t)pi * D_DIM) + c * 4;
    float4 A0 = arow[0], A1 = arow[1], A2 = arow[2], A3 = arow[3];
    float4 P0 = prow[0], P1 = prow[1], P2 = prow[2], P3 = prow[3];

    // --- gathers: 8 independent 16B loads, all in flight together ---
    int nidx[8] = {nlo.x, nlo.y, nlo.z, nlo.w, nhi.x, nhi.y, nhi.z, nhi.w};
    uint4 q[8];
    #pragma unroll
    for (int p = 0; p < 8; ++p)
        q[p] = ((const uint4*)(tab + (size_t)nidx[p] * 64))[c];

    // --- a.p: partial over this lane's 16-elem chunk, 3-shfl in-group reduce
    float app = A0.x * P0.x + A0.y * P0.y + A0.z * P0.z + A0.w * P0.w
              + A1.x * P1.x + A1.y * P1.y + A1.z * P1.z + A1.w * P1.w
              + A2.x * P2.x + A2.y * P2.y + A2.z * P2.z + A2.w * P2.w
              + A3.x * P3.x + A3.y * P3.y + A3.z * P3.z + A3.w * P3.w;
    app += __shfl_xor(app, 1, 64);
    app += __shfl_xor(app, 2, 64);
    app += __shfl_xor(app, 4, 64);    // every lane: full exact a.p

    vfloat2 Av0 = {A0.x, A0.y}, Av1 = {A0.z, A0.w};
    vfloat2 Av2 = {A1.x, A1.y}, Av3 = {A1.z, A1.w};
    vfloat2 Av4 = {A2.x, A2.y}, Av5 = {A2.z, A2.w};
    vfloat2 Av6 = {A3.x, A3.y}, Av7 = {A3.z, A3.w};

    // --- 8 passes: s[p] = chunk-c partial dot of row g*8+p ---
    float s[8];
    #pragma unroll
    for (int p = 0; p < 8; ++p) {
        uint4 qq = q[p];
        vfloat2 f0 = __builtin_amdgcn_cvt_pk_f32_fp8(qq.x, false);
        vfloat2 f1 = __builtin_amdgcn_cvt_pk_f32_fp8(qq.x, true);
        vfloat2 f2 = __builtin_amdgcn_cvt_pk_f32_fp8(qq.y, false);
        vfloat2 f3 = __builtin_amdgcn_cvt_pk_f32_fp8(qq.y, true);
        vfloat2 f4 = __builtin_amdgcn_cvt_pk_f32_fp8(qq.z, false);
        vfloat2 f5 = __builtin_amdgcn_cvt_pk_f32_fp8(qq.z, true);
        vfloat2 f6 = __builtin_amdgcn_cvt_pk_f32_fp8(qq.w, false);
        vfloat2 f7 = __builtin_amdgcn_cvt_pk_f32_fp8(qq.w, true);
        vfloat2 acc = f0 * Av0;       // v_pk_fma_f32 chain
        acc += f1 * Av1;
        acc += f2 * Av2;
        acc += f3 * Av3;
        acc += f4 * Av4;
        acc += f5 * Av5;
        acc += f6 * Av6;
        acc += f7 * Av7;
        s[p] = acc.x + acc.y;
    }

    // --- butterfly transpose-reduce: lane (g,c) ends with full dot of row
    // g*8+c (= its own lane id). 7 shfl total. All partner lanes are within
    // the 8-lane group, and selection indices are compile-time (no scratch).
    const bool h4 = (c & 4) != 0;
    float t0 = (h4 ? s[4] : s[0]) + __shfl_xor(h4 ? s[0] : s[4], 4, 64);
    float t1 = (h4 ? s[5] : s[1]) + __shfl_xor(h4 ? s[1] : s[5], 4, 64);
    float t2 = (h4 ? s[6] : s[2]) + __shfl_xor(h4 ? s[2] : s[6], 4, 64);
    float t3 = (h4 ? s[7] : s[3]) + __shfl_xor(h4 ? s[3] : s[7], 4, 64);
    const bool h2 = (c & 2) != 0;
    float u0 = (h2 ? t2 : t0) + __shfl_xor(h2 ? t0 : t2, 2, 64);
    float u1 = (h2 ? t3 : t1) + __shfl_xor(h2 ? t1 : t3, 2, 64);
    const bool h1 = (c & 1) != 0;
    float inner = (h1 ? u1 : u0) + __shfl_xor(h1 ? u0 : u1, 1, 64);

    inner -= app;                // inner[lane] = a.(n_lane - p), exact a.p

    float m  = wave_reduce_max(inner);
    float se = wave_reduce_sum(__expf(inner - m));
    float lse = m + __logf(se);
    float per = (lse > 0.f) ? lse + log1pf(__expf(-lse)) : log1pf(__expf(lse));

    if (lane == 0) red[wave] = per * (1.0f / (float)A_SZ);    // pre-scaled
    __syncthreads();
    if (threadIdx.x == 0) {
        float bs = red[0] + red[1] + red[2] + red[3];
        partial[CONV_BLK + blockIdx.x] = bs;
        __threadfence();         // make partial visible at device scope
        unsigned prev = __hip_atomic_fetch_add(counter, 1u, __ATOMIC_ACQ_REL,
                                               __HIP_MEMORY_SCOPE_AGENT);
        last_flag = (prev == NBLK - 1) ? 1u : 0u;
    }
    __syncthreads();
    if (last_flag) {             // last block: deterministic final sum
        float v = 0.f;
        for (int j = threadIdx.x; j < NPART; j += 256)
            v += __hip_atomic_load(&partial[j], __ATOMIC_RELAXED,
                                   __HIP_MEMORY_SCOPE_AGENT);
        v = wave_reduce_sum(v);
        if (lane == 0) red[wave] = v;
        __syncthreads();
        if (threadIdx.x == 0)
            out[0] = red[0] + red[1] + red[2] + red[3];
    }
}

// ---- fp32 fallback (used only if ws_size can't hold the fp8 table) ----
__global__ __launch_bounds__(256) void f32_kernel(const float* __restrict__ embed,
                                                  const int* __restrict__ anc_ind,
                                                  const int* __restrict__ pos_ind,
                                                  const int* __restrict__ neg_ind,
                                                  float* __restrict__ partial) {
    __shared__ __align__(16) float a_lds[4][D_DIM];
    __shared__ float red[4];
    const int wave = threadIdx.x >> 6;
    const int lane = threadIdx.x & 63;
    const int gw   = blockIdx.x * 4 + wave;

    float acc_l2 = 0.f;
    #pragma unroll
    for (int r = 0; r < 2; ++r) {
        const int row = gw * 2 + r;
        const float2* rr = (const float2*)(embed + (size_t)row * D_DIM);
        float2 v = rr[lane];
        acc_l2 += sqrtf(wave_reduce_sum(v.x * v.x + v.y * v.y));
    }
    const int i  = gw;
    const int ai = anc_ind[i];
    const int pi = pos_ind[i];
    const int ni = neg_ind[(size_t)i * K_SZ + lane];
    const float2* ar = (const float2*)(embed + (size_t)ai * D_DIM);
    const float2* pr = (const float2*)(embed + (size_t)pi * D_DIM);
    float2 a2 = ar[lane];
    float2 p2 = pr[lane];
    a_lds[wave][2 * lane]     = a2.x;
    a_lds[wave][2 * lane + 1] = a2.y;
    float ap = wave_reduce_sum(a2.x * p2.x + a2.y * p2.y);
    const float4* nr = (const float4*)(embed + (size_t)ni * D_DIM);
    const float4* al = (const float4*)a_lds[wave];
    float s0 = 0.f, s1 = 0.f, s2 = 0.f, s3 = 0.f;
    #pragma unroll
    for (int j = 0; j < D_DIM / 4; j += 4) {
        float4 n0 = nr[j], n1 = nr[j + 1], n2 = nr[j + 2], n3 = nr[j + 3];
        float4 a0 = al[j], a1 = al[j + 1], a2v = al[j + 2], a3 = al[j + 3];
        s0 += a0.x * n0.x + a0.y * n0.y + a0.z * n0.z + a0.w * n0.w;
        s1 += a1.x * n1.x + a1.y * n1.y + a1.z * n1.z + a1.w * n1.w;
        s2 += a2v.x * n2.x + a2v.y * n2.y + a2v.z * n2.z + a2v.w * n2.w;
        s3 += a3.x * n3.x + a3.y * n3.y + a3.z * n3.z + a3.w * n3.w;
    }
    float inner = (s0 + s1) + (s2 + s3) - ap;
    float m  = wave_reduce_max(inner);
    float se = wave_reduce_sum(__expf(inner - m));
    float lse = m + __logf(se);
    float per = (lse > 0.f) ? lse + log1pf(__expf(-lse)) : log1pf(__expf(lse));
    float combined = per * (1.0f / (float)A_SZ) + acc_l2 * (L2_REG_F / (float)B_SZ);
    if (lane == 0) red[wave] = combined;
    __syncthreads();
    if (threadIdx.x == 0)
        partial[blockIdx.x] = red[0] + red[1] + red[2] + red[3];
}

__global__ __launch_bounds__(256) void finalize_kernel(const float* __restrict__ partial,
                                                       int n, float* __restrict__ out) {
    __shared__ float red[4];
    const int wave = threadIdx.x >> 6;
    const int lane = threadIdx.x & 63;
    float v = 0.f;
    for (int j = threadIdx.x; j < n; j += 256) v += partial[j];
    v = wave_reduce_sum(v);
    if (lane == 0) red[wave] = v;
    __syncthreads();
    if (threadIdx.x == 0)
        out[0] = red[0] + red[1] + red[2] + red[3];
}

extern "C" void kernel_launch(void* const* d_in, const int* in_sizes, int n_in,
                              void* d_out, int out_size, void* d_ws, size_t ws_size,
                              hipStream_t stream) {
    const float* embed = (const float*)d_in[0];
    const int*   anc   = (const int*)d_in[1];
    const int*   pos   = (const int*)d_in[2];
    const int*   neg   = (const int*)d_in[3];
    float* out = (float*)d_out;

    const size_t tab_bytes = (size_t)B_SZ * D_DIM; // 2 MB fp8
    const size_t need = tab_bytes + NPART * sizeof(float) + sizeof(unsigned);

    if (ws_size >= need) {
        unsigned short* tab = (unsigned short*)d_ws;
        float* partial = (float*)((char*)d_ws + tab_bytes); // [conv | npair]
        unsigned* counter = (unsigned*)((char*)d_ws + tab_bytes + NPART * sizeof(float));
        convert_kernel<<<CONV_BLK, 256, 0, stream>>>(embed, tab, partial, counter);
        npair_kernel<<<NBLK, 256, 0, stream>>>(embed, tab, anc, pos, neg,
                                               partial, counter, out);
    } else {
        float* partial = (float*)d_ws;
        f32_kernel<<<NBLK, 256, 0, stream>>>(embed, anc, pos, neg, partial);
        finalize_kernel<<<1, 256, 0, stream>>>(partial, NBLK, out);
    }
}

// Round 4
// 91.202 us; speedup vs baseline: 1.6288x; 1.6288x over previous
//
#include <hip/hip_runtime.h>
#include <math.h>

#define B_SZ 16384
#define D_DIM 128
#define A_SZ 8192
#define K_SZ 64
#define L2_REG_F 0.25f
#define NBLK 2048      // fused kernel blocks: 4 waves/block, 1 anchor/wave

__device__ __forceinline__ float wave_reduce_sum(float v) {
    #pragma unroll
    for (int off = 32; off > 0; off >>= 1)
        v += __shfl_xor(v, off, 64);
    return v;
}

__device__ __forceinline__ float wave_reduce_max(float v) {
    #pragma unroll
    for (int off = 32; off > 0; off >>= 1)
        v = fmaxf(v, __shfl_xor(v, off, 64));
    return v;
}

__device__ __forceinline__ float dot4(float4 a, float4 b) {
    return a.x * b.x + a.y * b.y + a.z * b.z + a.w * b.w;
}

// Single fused kernel (no convert pass, no fences/atomics):
//  - wave = one anchor. 8-lane group g cooperates on negative rows g*8+p.
//    fp32 row = 512 B = 4 lines; quarter q: lane (g,c) reads float4 (c+8q)
//    -> each gather instruction covers 8 rows x one FULL 128B line
//    (zero line-level overfetch, unlike one-lane-per-row).
//  - per-pass partials s[p] reduced by the HW-validated 3-round butterfly
//    (R2, absmax 0.0): lane (g,c) ends with the full dot of row g*8+c.
//  - a/p read in the same chunk layout (per instruction: one broadcast line).
//  - L2-norm term fused: 2 embed rows/wave, streams the whole table (also
//    warms L3 for the gathers).
//  - per-block plain store; kernel boundary publishes to finalize_kernel.
__global__ __launch_bounds__(256) void fused_kernel(const float* __restrict__ embed,
                                                    const int* __restrict__ anc_ind,
                                                    const int* __restrict__ pos_ind,
                                                    const int* __restrict__ neg_ind,
                                                    float* __restrict__ partial) {
    __shared__ float red[4];
    const int wave = threadIdx.x >> 6;
    const int lane = threadIdx.x & 63;
    const int i    = blockIdx.x * 4 + wave;          // anchor id 0..8191
    const int g    = lane >> 3;   // group 0..7: rows g*8 .. g*8+7
    const int c    = lane & 7;    // chunk-lane 0..7 within the group

    // ---- independent loads first ----
    const int4* nb = (const int4*)(neg_ind + (size_t)i * K_SZ + g * 8);
    int4 nlo = nb[0], nhi = nb[1];                   // this group's 8 row ids

    const int ai = anc_ind[i];                       // wave-uniform
    const int pi = pos_ind[i];
    const float4* a4 = (const float4*)(embed + (size_t)ai * D_DIM);
    const float4* p4 = (const float4*)(embed + (size_t)pi * D_DIM);
    // lane's 4 chunk positions: c, c+8, c+16, c+24 (one per row-quarter)
    float4 A0 = a4[c], A1 = a4[c + 8], A2 = a4[c + 16], A3 = a4[c + 24];
    float4 P0 = p4[c], P1 = p4[c + 8], P2 = p4[c + 16], P3 = p4[c + 24];

    // norm rows: 8 per block, 2 per wave; half-wave per row, float4 per lane
    const int r0   = blockIdx.x * 8 + wave * 2;
    const int half = lane >> 5;                      // 0 -> r0, 1 -> r0+1
    const int hl   = lane & 31;
    float4 nv = ((const float4*)(embed + (size_t)(r0 + half) * D_DIM))[hl];

    // ---- gathers + per-pass partial dots (4 full-line loads per pass) ----
    int nidx[8] = {nlo.x, nlo.y, nlo.z, nlo.w, nhi.x, nhi.y, nhi.z, nhi.w};
    float s[8];
    #pragma unroll
    for (int p = 0; p < 8; ++p) {
        const float4* nr = (const float4*)(embed + (size_t)nidx[p] * D_DIM);
        float4 n0 = nr[c], n1 = nr[c + 8], n2 = nr[c + 16], n3 = nr[c + 24];
        s[p] = dot4(A0, n0) + dot4(A1, n1) + dot4(A2, n2) + dot4(A3, n3);
    }

    // ---- a.p: lane covers chunks {c+8q}; 8-lane group covers all 32 ----
    float app = dot4(A0, P0) + dot4(A1, P1) + dot4(A2, P2) + dot4(A3, P3);
    app += __shfl_xor(app, 1, 64);
    app += __shfl_xor(app, 2, 64);
    app += __shfl_xor(app, 4, 64);    // every lane: full exact a.p

    // ---- norm term: reduce within each 32-lane half, then combine ----
    float sq = nv.x * nv.x + nv.y * nv.y + nv.z * nv.z + nv.w * nv.w;
    #pragma unroll
    for (int off = 16; off > 0; off >>= 1)
        sq += __shfl_xor(sq, off, 64);               // stays within each half
    float nrm = sqrtf(sq);
    nrm += __shfl_xor(nrm, 32, 64);                  // both rows' norms

    // ---- 3-round butterfly transpose-reduce (validated in R2, absmax 0.0):
    // lane (g,c) ends with the full dot of row g*8+c (= its own lane id).
    const bool h4 = (c & 4) != 0;
    float t0 = (h4 ? s[4] : s[0]) + __shfl_xor(h4 ? s[0] : s[4], 4, 64);
    float t1 = (h4 ? s[5] : s[1]) + __shfl_xor(h4 ? s[1] : s[5], 4, 64);
    float t2 = (h4 ? s[6] : s[2]) + __shfl_xor(h4 ? s[2] : s[6], 4, 64);
    float t3 = (h4 ? s[7] : s[3]) + __shfl_xor(h4 ? s[3] : s[7], 4, 64);
    const bool h2 = (c & 2) != 0;
    float u0 = (h2 ? t2 : t0) + __shfl_xor(h2 ? t0 : t2, 2, 64);
    float u1 = (h2 ? t3 : t1) + __shfl_xor(h2 ? t1 : t3, 2, 64);
    const bool h1 = (c & 1) != 0;
    float inner = (h1 ? u1 : u0) + __shfl_xor(h1 ? u0 : u1, 1, 64);

    inner -= app;                 // inner[lane] = a.(n_lane - p), exact

    // ---- stable logaddexp(0, logsumexp(inner)) over the 64 negatives ----
    float m  = wave_reduce_max(inner);
    float se = wave_reduce_sum(__expf(inner - m));
    float lse = m + __logf(se);
    float per = (lse > 0.f) ? lse + log1pf(__expf(-lse)) : log1pf(__expf(lse));

    if (lane == 0)
        red[wave] = per * (1.0f / (float)A_SZ) + nrm * (L2_REG_F / (float)B_SZ);
    __syncthreads();
    if (threadIdx.x == 0)
        partial[blockIdx.x] = red[0] + red[1] + red[2] + red[3];  // plain store
}

__global__ __launch_bounds__(256) void finalize_kernel(const float* __restrict__ partial,
                                                       int n, float* __restrict__ out) {
    __shared__ float red[4];
    const int wave = threadIdx.x >> 6;
    const int lane = threadIdx.x & 63;
    float v = 0.f;
    for (int j = threadIdx.x; j < n; j += 256) v += partial[j];
    v = wave_reduce_sum(v);
    if (lane == 0) red[wave] = v;
    __syncthreads();
    if (threadIdx.x == 0)
        out[0] = red[0] + red[1] + red[2] + red[3];
}

extern "C" void kernel_launch(void* const* d_in, const int* in_sizes, int n_in,
                              void* d_out, int out_size, void* d_ws, size_t ws_size,
                              hipStream_t stream) {
    const float* embed = (const float*)d_in[0];
    const int*   anc   = (const int*)d_in[1];
    const int*   pos   = (const int*)d_in[2];
    const int*   neg   = (const int*)d_in[3];
    float* out = (float*)d_out;

    float* partial = (float*)d_ws;   // NBLK floats = 8 KB
    fused_kernel<<<NBLK, 256, 0, stream>>>(embed, anc, pos, neg, partial);
    finalize_kernel<<<1, 256, 0, stream>>>(partial, NBLK, out);
}